// Round 3
// baseline (769.324 us; speedup 1.0000x reference)
//
#include <hip/hip_runtime.h>
#include <hip/hip_bf16.h>

#define DI 2048
#define DO 2048
#define NB 4096
#define MEXP 8
#define LN_EPS 1e-5f

#define BM 128
#define BN 128
#define BK 64

using frag_ab = __attribute__((ext_vector_type(8))) short;  // 8 bf16
using f32x4   = __attribute__((ext_vector_type(4))) float;

__device__ __forceinline__ unsigned short f2bf(float f) {
  unsigned int u = __float_as_uint(f);
  u += 0x7fffu + ((u >> 16) & 1u);   // round-to-nearest-even
  return (unsigned short)(u >> 16);
}

// fp32 -> bf16, 8 elems/thread, exact grid (n divisible by 2048)
__global__ __launch_bounds__(256) void cvt_bf16_8(const float* __restrict__ src,
                                                  unsigned short* __restrict__ dst) {
  size_t i = ((size_t)blockIdx.x * 256 + threadIdx.x) * 8;
  float4 a = *(const float4*)(src + i);
  float4 b = *(const float4*)(src + i + 4);
  alignas(16) unsigned short u[8] = {f2bf(a.x), f2bf(a.y), f2bf(a.z), f2bf(a.w),
                                     f2bf(b.x), f2bf(b.y), f2bf(b.z), f2bf(b.w)};
  *(uint4*)(dst + i) = *(const uint4*)u;
}

// premix[b,i] = sum_m pW[b,m] * sum_j Ws[m,i,j] * x[b,j]
// A = x_bf16 [NB][DI], B = Ws_bf16 [MEXP][DO][DI] (B^T layout: row = out col, K contiguous)
__global__ __launch_bounds__(256, 2) void gemm_moe(
    const unsigned short* __restrict__ Xb,
    const unsigned short* __restrict__ Wb,
    const float* __restrict__ pW,
    float* __restrict__ premix) {
  __shared__ unsigned short ldsA[BM * BK];
  __shared__ unsigned short ldsB[BN * BK];
  __shared__ float ldsPW[BM][MEXP];

  const int t  = threadIdx.x;
  const int l  = t & 63;
  const int w  = t >> 6;
  const int wr = (w >> 1) * 64;   // wave row offset in tile
  const int wc = (w & 1) * 64;    // wave col offset in tile
  const int lr = l & 15;          // fragment lane row/col
  const int lg = l >> 4;          // k-group (0..3)

  // XCD-aware swizzle (nwg = 512, divisible by 8 -> simple form is bijective)
  const int nwg = gridDim.x;
  const int cpx = nwg >> 3;
  const int bid = blockIdx.x;
  const int swz = (bid & 7) * cpx + (bid >> 3);
  const int brow = (swz >> 4) * BM;   // 32 row tiles
  const int bcol = (swz & 15) * BN;   // 16 col tiles

  for (int i = t; i < BM * MEXP; i += 256)
    ldsPW[i >> 3][i & 7] = pW[(size_t)(brow + (i >> 3)) * MEXP + (i & 7)];

  f32x4 mix[4][4] = {};

  for (int m = 0; m < MEXP; ++m) {
    const unsigned short* Wm = Wb + (size_t)m * DO * DI;
    f32x4 part[4][4] = {};
    for (int kk = 0; kk < DI; kk += BK) {
      // stage A and B tiles: 16 KB each, 4 issues/thread each, width-16 direct-to-LDS
#pragma unroll
      for (int q = 0; q < 4; ++q) {
        const int e   = q * 2048 + t * 8;  // elem index in [128][64] tile
        const int row = e >> 6;
        const int kx  = e & 63;
        __builtin_amdgcn_global_load_lds(
            (const __attribute__((address_space(1))) void*)(Xb + (size_t)(brow + row) * DI + kk + kx),
            (__attribute__((address_space(3))) void*)(&ldsA[e]), 16, 0, 0);
        __builtin_amdgcn_global_load_lds(
            (const __attribute__((address_space(1))) void*)(Wm + (size_t)(bcol + row) * DI + kk + kx),
            (__attribute__((address_space(3))) void*)(&ldsB[e]), 16, 0, 0);
      }
      __syncthreads();   // compiler emits vmcnt(0) drain before barrier
#pragma unroll
      for (int ks = 0; ks < 2; ++ks) {
        frag_ab af[4], bfr[4];
#pragma unroll
        for (int i = 0; i < 4; ++i) {
          af[i]  = *(const frag_ab*)&ldsA[(wr + i * 16 + lr) * BK + ks * 32 + lg * 8];
          bfr[i] = *(const frag_ab*)&ldsB[(wc + i * 16 + lr) * BK + ks * 32 + lg * 8];
        }
#pragma unroll
        for (int mi = 0; mi < 4; ++mi)
#pragma unroll
          for (int ni = 0; ni < 4; ++ni)
            part[mi][ni] = __builtin_amdgcn_mfma_f32_16x16x32_bf16(
                af[mi], bfr[ni], part[mi][ni], 0, 0, 0);
      }
      __syncthreads();
    }
    // fold expert m into mix with per-row pW (C/D row = (l>>4)*4 + reg)
#pragma unroll
    for (int mi = 0; mi < 4; ++mi)
#pragma unroll
      for (int r = 0; r < 4; ++r) {
        const float p = ldsPW[wr + mi * 16 + lg * 4 + r][m];
#pragma unroll
        for (int ni = 0; ni < 4; ++ni)
          mix[mi][ni][r] += p * part[mi][ni][r];
      }
  }

#pragma unroll
  for (int mi = 0; mi < 4; ++mi)
#pragma unroll
    for (int ni = 0; ni < 4; ++ni)
#pragma unroll
      for (int r = 0; r < 4; ++r) {
        const size_t row = brow + wr + mi * 16 + lg * 4 + r;
        const size_t col = bcol + wc + ni * 16 + lr;
        premix[row * DO + col] = mix[mi][ni][r];
      }
}

// z = gW*premix + gb*(pb@bs); LayerNorm over DO; ELU
__global__ __launch_bounds__(256) void ln_elu(
    const float* __restrict__ premix, const float* __restrict__ gW,
    const float* __restrict__ gb, const float* __restrict__ pb,
    const float* __restrict__ bs, float* __restrict__ out) {
  const int b = blockIdx.x;
  const int t = threadIdx.x;
  const float* pm  = premix + (size_t)b * DO;
  const float* gWr = gW + (size_t)b * DO;
  const float* gbr = gb + (size_t)b * DO;
  float pbv[MEXP];
#pragma unroll
  for (int m = 0; m < MEXP; ++m) pbv[m] = pb[(size_t)b * MEXP + m];

  float4 zv[2];
  float s = 0.f, ss = 0.f;
#pragma unroll
  for (int c = 0; c < 2; ++c) {
    const int i = (t + c * 256) * 4;
    float4 pm4 = *(const float4*)(pm + i);
    float4 gW4 = *(const float4*)(gWr + i);
    float4 gb4 = *(const float4*)(gbr + i);
    float bx = 0.f, by = 0.f, bz = 0.f, bw = 0.f;
#pragma unroll
    for (int m = 0; m < MEXP; ++m) {
      float4 bs4 = *(const float4*)(bs + (size_t)m * DO + i);
      bx += pbv[m] * bs4.x; by += pbv[m] * bs4.y;
      bz += pbv[m] * bs4.z; bw += pbv[m] * bs4.w;
    }
    float4 z;
    z.x = gW4.x * pm4.x + gb4.x * bx;
    z.y = gW4.y * pm4.y + gb4.y * by;
    z.z = gW4.z * pm4.z + gb4.z * bz;
    z.w = gW4.w * pm4.w + gb4.w * bw;
    zv[c] = z;
    s  += z.x + z.y + z.z + z.w;
    ss += z.x * z.x + z.y * z.y + z.z * z.z + z.w * z.w;
  }
#pragma unroll
  for (int off = 32; off > 0; off >>= 1) {
    s  += __shfl_down(s, off);
    ss += __shfl_down(ss, off);
  }
  __shared__ float red[2][4];
  if ((t & 63) == 0) { red[0][t >> 6] = s; red[1][t >> 6] = ss; }
  __syncthreads();
  const float st  = red[0][0] + red[0][1] + red[0][2] + red[0][3];
  const float sst = red[1][0] + red[1][1] + red[1][2] + red[1][3];
  const float mu  = st * (1.f / DO);
  const float var = sst * (1.f / DO) - mu * mu;
  const float inv = rsqrtf(var + LN_EPS);
  float* outr = out + (size_t)b * DO;
#pragma unroll
  for (int c = 0; c < 2; ++c) {
    const int i = (t + c * 256) * 4;
    float4 z = zv[c];
    float4 y;
    y.x = (z.x - mu) * inv; y.y = (z.y - mu) * inv;
    y.z = (z.z - mu) * inv; y.w = (z.w - mu) * inv;
    y.x = y.x > 0.f ? y.x : expm1f(y.x);
    y.y = y.y > 0.f ? y.y : expm1f(y.y);
    y.z = y.z > 0.f ? y.z : expm1f(y.z);
    y.w = y.w > 0.f ? y.w : expm1f(y.w);
    *(float4*)(outr + i) = y;
  }
}

extern "C" void kernel_launch(void* const* d_in, const int* in_sizes, int n_in,
                              void* d_out, int out_size, void* d_ws, size_t ws_size,
                              hipStream_t stream) {
  const float* x  = (const float*)d_in[0];
  const float* Ws = (const float*)d_in[1];
  const float* bs = (const float*)d_in[2];
  const float* pW = (const float*)d_in[3];
  const float* pb = (const float*)d_in[4];
  const float* gW = (const float*)d_in[5];
  const float* gb = (const float*)d_in[6];
  float* out = (float*)d_out;

  unsigned short* xb = (unsigned short*)d_ws;                                 // 16 MB
  unsigned short* Wb = (unsigned short*)((char*)d_ws + ((size_t)16 << 20));   // 64 MB
  float* premix      = (float*)((char*)d_ws + ((size_t)80 << 20));            // 32 MB

  cvt_bf16_8<<<4096, 256, 0, stream>>>(x, xb);     // 4096*2048 / (8*256)
  cvt_bf16_8<<<16384, 256, 0, stream>>>(Ws, Wb);   // 8*2048*2048 / (8*256)
  gemm_moe<<<512, 256, 0, stream>>>(xb, Wb, pW, premix);
  ln_elu<<<4096, 256, 0, stream>>>(premix, gW, gb, pb, bs, out);
}

// Round 4
// 626.805 us; speedup vs baseline: 1.2274x; 1.2274x over previous
//
#include <hip/hip_runtime.h>
#include <hip/hip_bf16.h>

#define DI 2048
#define DO 2048
#define NB 4096
#define MEXP 8
#define KTOT (MEXP * DI)   // 16384
#define LN_EPS 1e-5f

#define BM 128
#define BN 128
#define BK 64

using frag_ab = __attribute__((ext_vector_type(8))) short;  // 8 bf16
using f32x4   = __attribute__((ext_vector_type(4))) float;

__device__ __forceinline__ unsigned short f2bf(float f) {
  unsigned int u = __float_as_uint(f);
  u += 0x7fffu + ((u >> 16) & 1u);   // round-to-nearest-even
  return (unsigned short)(u >> 16);
}

// ---------- prep kernels ----------

// A'[b, m*DI+j] = bf16(pW[b,m] * x[b,j]).  grid 32768 (= NB*MEXP), 256 thr, 8 elems/thr
__global__ __launch_bounds__(256) void aprep(const float* __restrict__ x,
                                             const float* __restrict__ pW,
                                             unsigned short* __restrict__ Ab) {
  const int bid = blockIdx.x;
  const int b = bid >> 3, m = bid & 7;
  const int j = threadIdx.x * 8;
  const float p = pW[(size_t)b * MEXP + m];
  float4 a = *(const float4*)(x + (size_t)b * DI + j);
  float4 c = *(const float4*)(x + (size_t)b * DI + j + 4);
  alignas(16) unsigned short u[8] = {
      f2bf(p * a.x), f2bf(p * a.y), f2bf(p * a.z), f2bf(p * a.w),
      f2bf(p * c.x), f2bf(p * c.y), f2bf(p * c.z), f2bf(p * c.w)};
  *(uint4*)(Ab + (size_t)b * KTOT + (size_t)m * DI + j) = *(const uint4*)u;
}

// fp32 -> bf16, 8 elems/thread
__global__ __launch_bounds__(256) void cvt_bf16_8(const float* __restrict__ src,
                                                  unsigned short* __restrict__ dst) {
  size_t i = ((size_t)blockIdx.x * 256 + threadIdx.x) * 8;
  float4 a = *(const float4*)(src + i);
  float4 b = *(const float4*)(src + i + 4);
  alignas(16) unsigned short u[8] = {f2bf(a.x), f2bf(a.y), f2bf(a.z), f2bf(a.w),
                                     f2bf(b.x), f2bf(b.y), f2bf(b.z), f2bf(b.w)};
  *(uint4*)(dst + i) = *(const uint4*)u;
}

// ---------- main GEMM (path a): premix_part = A'[.,kbeg:kend] @ B^T ----------
// A' [NB][KTOT] bf16 (pW folded), Bm [MEXP][DO][DI] bf16 (B^T per expert, K contig)
// LDS tiles are XOR-swizzled (T2): global source chunk pre-swizzled, linear LDS dest
// (rule 21), reads apply the same involution -> 16-way conflict becomes <=2-way.
__global__ __launch_bounds__(256, 4) void gemm_bt(
    const unsigned short* __restrict__ A,
    const unsigned short* __restrict__ Bm,
    float* __restrict__ dst,
    int kbeg, int kend) {
  __shared__ unsigned short ldsA[BM * BK];
  __shared__ unsigned short ldsB[BN * BK];

  const int t  = threadIdx.x;
  const int l  = t & 63;
  const int w  = t >> 6;
  const int wr = (w >> 1) * 64;
  const int wc = (w & 1) * 64;
  const int lr = l & 15;
  const int lg = l >> 4;

  // 512 output tiles; bid = tile | (khalf<<9) when gridDim==1024
  const int bid  = blockIdx.x;
  const int tile = bid & 511;
  const int half = bid >> 9;
  const int tswz = (tile & 7) * 64 + (tile >> 3);   // XCD-aware, bijective (512 % 8 == 0)
  const int brow = (tswz >> 4) * BM;
  const int bcol = (tswz & 15) * BN;
  const int k0 = kbeg + half * ((kend - kbeg) >> (gridDim.x > 512 ? 1 : 31));
  // (when gridDim==512, half==0 and k-range is [kbeg,kend))
  const int kend_l = (gridDim.x > 512) ? (k0 + ((kend - kbeg) >> 1)) : kend;
  float* dst_l = dst + (size_t)half * NB * DO;

  f32x4 acc[4][4] = {};

  for (int kk = k0; kk < kend_l; kk += BK) {
    const int m  = kk >> 11;          // expert of this K-tile (BK divides DI)
    const int j0 = kk & (DI - 1);
    const unsigned short* Asrc = A + (size_t)brow * KTOT + kk;
    const unsigned short* Bsrc = Bm + ((size_t)m * DO + bcol) * DI + j0;
#pragma unroll
    for (int q = 0; q < 4; ++q) {
      const int c   = q * 256 + t;        // 16B chunk index in [128 rows][8 chunks]
      const int row = c >> 3;
      const int cs  = c ^ ((c >> 3) & 7); // inverse-swizzled source chunk
      const int j8  = (cs & 7) * 8;
      __builtin_amdgcn_global_load_lds(
          (const __attribute__((address_space(1))) void*)(Asrc + (size_t)row * KTOT + j8),
          (__attribute__((address_space(3))) void*)(&ldsA[c * 8]), 16, 0, 0);
      __builtin_amdgcn_global_load_lds(
          (const __attribute__((address_space(1))) void*)(Bsrc + (size_t)row * DI + j8),
          (__attribute__((address_space(3))) void*)(&ldsB[c * 8]), 16, 0, 0);
    }
    __syncthreads();
#pragma unroll
    for (int ks = 0; ks < 2; ++ks) {
      frag_ab af[4], bf[4];
#pragma unroll
      for (int i = 0; i < 4; ++i) {
        const int ra = wr + i * 16 + lr;
        const int ea = (ra * BK + ks * 32 + lg * 8) ^ ((ra & 7) << 3);
        af[i] = *(const frag_ab*)&ldsA[ea];
        const int rb = wc + i * 16 + lr;
        const int eb = (rb * BK + ks * 32 + lg * 8) ^ ((rb & 7) << 3);
        bf[i] = *(const frag_ab*)&ldsB[eb];
      }
#pragma unroll
      for (int mi = 0; mi < 4; ++mi)
#pragma unroll
        for (int ni = 0; ni < 4; ++ni)
          acc[mi][ni] = __builtin_amdgcn_mfma_f32_16x16x32_bf16(
              af[mi], bf[ni], acc[mi][ni], 0, 0, 0);
    }
    __syncthreads();
  }

#pragma unroll
  for (int mi = 0; mi < 4; ++mi)
#pragma unroll
    for (int ni = 0; ni < 4; ++ni)
#pragma unroll
      for (int r = 0; r < 4; ++r) {
        const size_t row = brow + wr + mi * 16 + lg * 4 + r;
        const size_t col = bcol + wc + ni * 16 + lr;
        dst_l[row * DO + col] = acc[mi][ni][r];
      }
}

// ---------- fallback GEMM (path c): expert m-loop, pW in-kernel, swizzled LDS ----------
__global__ __launch_bounds__(256, 2) void gemm_moe_sw(
    const unsigned short* __restrict__ Xb,
    const unsigned short* __restrict__ Wb,
    const float* __restrict__ pW,
    float* __restrict__ premix) {
  __shared__ unsigned short ldsA[BM * BK];
  __shared__ unsigned short ldsB[BN * BK];
  __shared__ float ldsPW[BM][MEXP];

  const int t  = threadIdx.x;
  const int l  = t & 63;
  const int w  = t >> 6;
  const int wr = (w >> 1) * 64, wc = (w & 1) * 64;
  const int lr = l & 15, lg = l >> 4;

  const int bid = blockIdx.x;
  const int swz = (bid & 7) * 64 + (bid >> 3);
  const int brow = (swz >> 4) * BM;
  const int bcol = (swz & 15) * BN;

  for (int i = t; i < BM * MEXP; i += 256)
    ldsPW[i >> 3][i & 7] = pW[(size_t)(brow + (i >> 3)) * MEXP + (i & 7)];

  f32x4 mix[4][4] = {};
  for (int m = 0; m < MEXP; ++m) {
    const unsigned short* Wm = Wb + (size_t)m * DO * DI;
    f32x4 part[4][4] = {};
    for (int kk = 0; kk < DI; kk += BK) {
#pragma unroll
      for (int q = 0; q < 4; ++q) {
        const int c = q * 256 + t;
        const int row = c >> 3;
        const int cs = c ^ ((c >> 3) & 7);
        const int j8 = (cs & 7) * 8;
        __builtin_amdgcn_global_load_lds(
            (const __attribute__((address_space(1))) void*)(Xb + (size_t)(brow + row) * DI + kk + j8),
            (__attribute__((address_space(3))) void*)(&ldsA[c * 8]), 16, 0, 0);
        __builtin_amdgcn_global_load_lds(
            (const __attribute__((address_space(1))) void*)(Wm + (size_t)(bcol + row) * DI + kk + j8),
            (__attribute__((address_space(3))) void*)(&ldsB[c * 8]), 16, 0, 0);
      }
      __syncthreads();
#pragma unroll
      for (int ks = 0; ks < 2; ++ks) {
        frag_ab af[4], bfr[4];
#pragma unroll
        for (int i = 0; i < 4; ++i) {
          const int ra = wr + i * 16 + lr;
          const int ea = (ra * BK + ks * 32 + lg * 8) ^ ((ra & 7) << 3);
          af[i] = *(const frag_ab*)&ldsA[ea];
          const int rb = wc + i * 16 + lr;
          const int eb = (rb * BK + ks * 32 + lg * 8) ^ ((rb & 7) << 3);
          bfr[i] = *(const frag_ab*)&ldsB[eb];
        }
#pragma unroll
        for (int mi = 0; mi < 4; ++mi)
#pragma unroll
          for (int ni = 0; ni < 4; ++ni)
            part[mi][ni] = __builtin_amdgcn_mfma_f32_16x16x32_bf16(
                af[mi], bfr[ni], part[mi][ni], 0, 0, 0);
      }
      __syncthreads();
    }
#pragma unroll
    for (int mi = 0; mi < 4; ++mi)
#pragma unroll
      for (int r = 0; r < 4; ++r) {
        const float p = ldsPW[wr + mi * 16 + lg * 4 + r][m];
#pragma unroll
        for (int ni = 0; ni < 4; ++ni)
          mix[mi][ni][r] += p * part[mi][ni][r];
      }
  }
#pragma unroll
  for (int mi = 0; mi < 4; ++mi)
#pragma unroll
    for (int ni = 0; ni < 4; ++ni)
#pragma unroll
      for (int r = 0; r < 4; ++r) {
        const size_t row = brow + wr + mi * 16 + lg * 4 + r;
        const size_t col = bcol + wc + ni * 16 + lr;
        premix[row * DO + col] = mix[mi][ni][r];
      }
}

// ---------- epilogue: z = gW*(p0[+p1]) + gb*(pb@bs); LN; ELU ----------
__global__ __launch_bounds__(256) void ln_elu(
    const float* __restrict__ p0, const float* __restrict__ p1, int nparts,
    const float* __restrict__ gW, const float* __restrict__ gb,
    const float* __restrict__ pb, const float* __restrict__ bs,
    float* __restrict__ out) {
  const int b = blockIdx.x;
  const int t = threadIdx.x;
  const float* pm0 = p0 + (size_t)b * DO;
  const float* pm1 = p1 + (size_t)b * DO;
  const float* gWr = gW + (size_t)b * DO;
  const float* gbr = gb + (size_t)b * DO;
  float pbv[MEXP];
#pragma unroll
  for (int m = 0; m < MEXP; ++m) pbv[m] = pb[(size_t)b * MEXP + m];

  float4 zv[2];
  float s = 0.f, ss = 0.f;
#pragma unroll
  for (int c = 0; c < 2; ++c) {
    const int i = (t + c * 256) * 4;
    float4 pm4 = *(const float4*)(pm0 + i);
    if (nparts == 2) {
      float4 q = *(const float4*)(pm1 + i);
      pm4.x += q.x; pm4.y += q.y; pm4.z += q.z; pm4.w += q.w;
    }
    float4 gW4 = *(const float4*)(gWr + i);
    float4 gb4 = *(const float4*)(gbr + i);
    float bx = 0.f, by = 0.f, bz = 0.f, bw = 0.f;
#pragma unroll
    for (int m = 0; m < MEXP; ++m) {
      float4 bs4 = *(const float4*)(bs + (size_t)m * DO + i);
      bx += pbv[m] * bs4.x; by += pbv[m] * bs4.y;
      bz += pbv[m] * bs4.z; bw += pbv[m] * bs4.w;
    }
    float4 z;
    z.x = gW4.x * pm4.x + gb4.x * bx;
    z.y = gW4.y * pm4.y + gb4.y * by;
    z.z = gW4.z * pm4.z + gb4.z * bz;
    z.w = gW4.w * pm4.w + gb4.w * bw;
    zv[c] = z;
    s  += z.x + z.y + z.z + z.w;
    ss += z.x * z.x + z.y * z.y + z.z * z.z + z.w * z.w;
  }
#pragma unroll
  for (int off = 32; off > 0; off >>= 1) {
    s  += __shfl_down(s, off);
    ss += __shfl_down(ss, off);
  }
  __shared__ float red[2][4];
  if ((t & 63) == 0) { red[0][t >> 6] = s; red[1][t >> 6] = ss; }
  __syncthreads();
  const float st  = red[0][0] + red[0][1] + red[0][2] + red[0][3];
  const float sst = red[1][0] + red[1][1] + red[1][2] + red[1][3];
  const float mu  = st * (1.f / DO);
  const float var = sst * (1.f / DO) - mu * mu;
  const float inv = rsqrtf(var + LN_EPS);
  float* outr = out + (size_t)b * DO;
#pragma unroll
  for (int c = 0; c < 2; ++c) {
    const int i = (t + c * 256) * 4;
    float4 z = zv[c];
    if (nparts == 2) { /* already summed above */ }
    float4 y;
    y.x = (z.x - mu) * inv; y.y = (z.y - mu) * inv;
    y.z = (z.z - mu) * inv; y.w = (z.w - mu) * inv;
    y.x = y.x > 0.f ? y.x : expm1f(y.x);
    y.y = y.y > 0.f ? y.y : expm1f(y.y);
    y.z = y.z > 0.f ? y.z : expm1f(y.z);
    y.w = y.w > 0.f ? y.w : expm1f(y.w);
    *(float4*)(outr + i) = y;
  }
}

extern "C" void kernel_launch(void* const* d_in, const int* in_sizes, int n_in,
                              void* d_out, int out_size, void* d_ws, size_t ws_size,
                              hipStream_t stream) {
  const float* x  = (const float*)d_in[0];
  const float* Ws = (const float*)d_in[1];
  const float* bs = (const float*)d_in[2];
  const float* pW = (const float*)d_in[3];
  const float* pb = (const float*)d_in[4];
  const float* gW = (const float*)d_in[5];
  const float* gb = (const float*)d_in[6];
  float* out = (float*)d_out;

  const size_t MB = (size_t)1 << 20;

  if (ws_size >= 256 * MB) {
    // path a: A' (pW-folded) single GEMM K=16384, split-K=2
    unsigned short* Ab = (unsigned short*)d_ws;                         // 128 MB
    unsigned short* Wb = (unsigned short*)((char*)d_ws + 128 * MB);     //  64 MB
    float* pre0        = (float*)((char*)d_ws + 192 * MB);              //  32 MB
    float* pre1        = (float*)((char*)d_ws + 224 * MB);              //  32 MB
    aprep<<<NB * MEXP, 256, 0, stream>>>(x, pW, Ab);
    cvt_bf16_8<<<16384, 256, 0, stream>>>(Ws, Wb);
    gemm_bt<<<1024, 256, 0, stream>>>(Ab, Wb, pre0, 0, KTOT);  // pre1 = pre0 + NB*DO
    ln_elu<<<NB, 256, 0, stream>>>(pre0, pre1, 2, gW, gb, pb, bs, out);
  } else {
    // path c: expert-loop GEMM (112 MB ws)
    unsigned short* xb = (unsigned short*)d_ws;                         // 16 MB
    unsigned short* Wb = (unsigned short*)((char*)d_ws + 16 * MB);      // 64 MB
    float* pre0        = (float*)((char*)d_ws + 80 * MB);               // 32 MB
    cvt_bf16_8<<<4096, 256, 0, stream>>>(x, xb);
    cvt_bf16_8<<<16384, 256, 0, stream>>>(Ws, Wb);
    gemm_moe_sw<<<512, 256, 0, stream>>>(xb, Wb, pW, pre0);
    ln_elu<<<NB, 256, 0, stream>>>(pre0, pre0, 1, gW, gb, pb, bs, out);
  }
}